// Round 9
// baseline (1734.206 us; speedup 1.0000x reference)
//
#include <hip/hip_runtime.h>
#include <hip/hip_bf16.h>
#include <cstdint>

typedef __bf16 bf16;
typedef bf16 bf16x8 __attribute__((ext_vector_type(8)));
typedef float f32x4 __attribute__((ext_vector_type(4)));

#define NTOK 4096   // B*T
#define DLBL 512    // D_LABEL
#define NLAB 50

__device__ inline bf16x8 cvt8(float4 a, float4 b) {
  bf16x8 r;
  r[0] = (bf16)a.x; r[1] = (bf16)a.y; r[2] = (bf16)a.z; r[3] = (bf16)a.w;
  r[4] = (bf16)b.x; r[5] = (bf16)b.y; r[6] = (bf16)b.z; r[7] = (bf16)b.w;
  return r;
}

// async global->LDS, 16B per lane; LDS dest = wave-uniform base + lane*16
__device__ __forceinline__ void gl16(const bf16* g, void* l) {
  __builtin_amdgcn_global_load_lds(
      (const __attribute__((address_space(1))) void*)g,
      (__attribute__((address_space(3))) void*)l, 16, 0, 0);
}

// ---------------------------------------------------------------------------
// Fused prep (r6-proven): blocks [0,256) projA (transposed out),
// [256,512) projB (gathered, natural out), [512,6912) convW.
// ---------------------------------------------------------------------------
__device__ void projA_body(int bidx, const float* __restrict__ Wp,
                           const float* __restrict__ X,
                           const float* __restrict__ bv,
                           bf16* __restrict__ outT, char* lds) {
  char* ldsA = lds;           // [128 e][32 d] bf16, row stride 80B
  char* ldsB = lds + 10240;   // [64 tok][32 d] bf16, row stride 80B
  const int tid = threadIdx.x, l = tid & 63, w = tid >> 6;
  const int tokbase = (bidx >> 2) * 64;
  const int ebase   = (bidx & 3) * 128;
  const int wr = w & 1, wc = w >> 1;
  f32x4 acc[4][2] = {};
  const int arow = tid >> 1, ahalf = tid & 1;
  const int brow = tid >> 2, bgr = tid & 3;
  const float* aS = Wp + (size_t)(ebase + arow) * 1024 + ahalf * 16;
  const float* bS = X  + (size_t)(tokbase + brow) * 1024 + bgr * 8;
  const int lo = (l & 15) * 80 + (l >> 4) * 16;
  for (int kb = 0; kb < 1024; kb += 32) {
    float4 a0 = *(const float4*)(aS + kb);
    float4 a1 = *(const float4*)(aS + kb + 4);
    float4 a2 = *(const float4*)(aS + kb + 8);
    float4 a3 = *(const float4*)(aS + kb + 12);
    float4 b0 = *(const float4*)(bS + kb);
    float4 b1 = *(const float4*)(bS + kb + 4);
    *(bf16x8*)(ldsA + arow * 80 + ahalf * 32)      = cvt8(a0, a1);
    *(bf16x8*)(ldsA + arow * 80 + ahalf * 32 + 16) = cvt8(a2, a3);
    *(bf16x8*)(ldsB + brow * 80 + bgr * 16)        = cvt8(b0, b1);
    __syncthreads();
    bf16x8 aF[4], bF[2];
#pragma unroll
    for (int i = 0; i < 4; ++i) aF[i] = *(bf16x8*)(ldsA + (wr * 64 + i * 16) * 80 + lo);
#pragma unroll
    for (int j = 0; j < 2; ++j) bF[j] = *(bf16x8*)(ldsB + (wc * 32 + j * 16) * 80 + lo);
#pragma unroll
    for (int i = 0; i < 4; ++i)
#pragma unroll
      for (int j = 0; j < 2; ++j)
        acc[i][j] = __builtin_amdgcn_mfma_f32_16x16x32_bf16(aF[i], bF[j], acc[i][j], 0, 0, 0);
    __syncthreads();
  }
#pragma unroll
  for (int i = 0; i < 4; ++i)
#pragma unroll
    for (int j = 0; j < 2; ++j)
#pragma unroll
      for (int r = 0; r < 4; ++r) {
        int eg = ebase + wr * 64 + i * 16 + (l >> 4) * 4 + r;
        int tg = tokbase + wc * 32 + j * 16 + (l & 15);
        outT[(size_t)eg * NTOK + tg] = (bf16)(acc[i][j][r] + bv[eg]);
      }
}

__device__ void projB_body(int bidx, const float* __restrict__ head,
                           const int* __restrict__ hidx,
                           const float* __restrict__ Wp,
                           const float* __restrict__ bv,
                           bf16* __restrict__ selO, char* lds) {
  char* ldsA = lds;           // [128 tok][32 d], stride 80
  char* ldsB = lds + 10240;   // [64 e][32 d], stride 80
  const int tid = threadIdx.x, l = tid & 63, w = tid >> 6;
  const int tokbase = (bidx >> 3) * 128;
  const int ebase   = (bidx & 7) * 64;
  const int wr = w & 1, wc = w >> 1;
  f32x4 acc[4][2] = {};
  const int arow = tid >> 1, ahalf = tid & 1;
  const int brow = tid >> 2, bgr = tid & 3;
  const int flat = tokbase + arow;
  const int bb = flat >> 11;
  const int hv = hidx[flat];
  const float* aS = head + ((size_t)bb * 2049 + hv) * 1024 + ahalf * 16;
  const float* bS = Wp + (size_t)(ebase + brow) * 1024 + bgr * 8;
  const int lo = (l & 15) * 80 + (l >> 4) * 16;
  for (int kb = 0; kb < 1024; kb += 32) {
    float4 a0 = *(const float4*)(aS + kb);
    float4 a1 = *(const float4*)(aS + kb + 4);
    float4 a2 = *(const float4*)(aS + kb + 8);
    float4 a3 = *(const float4*)(aS + kb + 12);
    float4 b0 = *(const float4*)(bS + kb);
    float4 b1 = *(const float4*)(bS + kb + 4);
    *(bf16x8*)(ldsA + arow * 80 + ahalf * 32)      = cvt8(a0, a1);
    *(bf16x8*)(ldsA + arow * 80 + ahalf * 32 + 16) = cvt8(a2, a3);
    *(bf16x8*)(ldsB + brow * 80 + bgr * 16)        = cvt8(b0, b1);
    __syncthreads();
    bf16x8 aF[4], bF[2];
#pragma unroll
    for (int i = 0; i < 4; ++i) aF[i] = *(bf16x8*)(ldsA + (wr * 64 + i * 16) * 80 + lo);
#pragma unroll
    for (int j = 0; j < 2; ++j) bF[j] = *(bf16x8*)(ldsB + (wc * 32 + j * 16) * 80 + lo);
#pragma unroll
    for (int i = 0; i < 4; ++i)
#pragma unroll
      for (int j = 0; j < 2; ++j)
        acc[i][j] = __builtin_amdgcn_mfma_f32_16x16x32_bf16(aF[i], bF[j], acc[i][j], 0, 0, 0);
    __syncthreads();
  }
#pragma unroll
  for (int i = 0; i < 4; ++i)
#pragma unroll
    for (int j = 0; j < 2; ++j)
#pragma unroll
      for (int r = 0; r < 4; ++r) {
        int tg = tokbase + wr * 64 + i * 16 + (l >> 4) * 4 + r;
        int eg = ebase + wc * 32 + j * 16 + (l & 15);
        selO[(size_t)tg * DLBL + eg] = (bf16)(acc[i][j][r] + bv[eg]);
      }
}

__global__ __launch_bounds__(256) void prep_k(const float* __restrict__ W,
                                              bf16* __restrict__ Wb,
                                              const float* __restrict__ dep_W,
                                              const float* __restrict__ dep,
                                              const float* __restrict__ dep_b,
                                              bf16* __restrict__ depT,
                                              const float* __restrict__ head,
                                              const int* __restrict__ hidx,
                                              const float* __restrict__ head_W,
                                              const float* __restrict__ head_b,
                                              bf16* __restrict__ selB) {
  __shared__ char lds[15360];
  const int b = blockIdx.x;
  if (b < 256) {
    projA_body(b, dep_W, dep, dep_b, depT, lds);
  } else if (b < 512) {
    projB_body(b - 256, head, hidx, head_W, head_b, selB, lds);
  } else {
    int i = (b - 512) * 256 + threadIdx.x;
    const float4* s = (const float4*)W + (size_t)i * 2;
    float4 a = s[0], c = s[1];
    *(bf16x8*)(Wb + (size_t)i * 8) = cvt8(a, c);
  }
}

// ---------------------------------------------------------------------------
// Kernel 4 v9: r5's proven structure (128d x 256tok, 16x16x32, BK=32,
// 3-buffer 72KB, 2 blocks/CU, counted vmcnt(3), 1 barrier/K-tile, 2-tile
// lead, setprio) with:
//   - STAGE issued at phase START (T3 recipe ordering; same hazard ledger)
//   - epilogue cross-wd LDS combine -> 4 parts slices (was 8)
//   - designated-reducer finish: per-(n,bx) atomic counter; the last of the
//     4 dz-blocks sums the 4 slices + bias and writes out (fixed add order
//     -> deterministic). Removes the fin_k dispatch.
// ---------------------------------------------------------------------------
__global__ __launch_bounds__(512, 2) void biaff_k(const bf16* __restrict__ Wb,
                                                  const bf16* __restrict__ sel,
                                                  const bf16* __restrict__ depT,
                                                  float* __restrict__ parts,
                                                  const float* __restrict__ bias,
                                                  float* __restrict__ out,
                                                  int* __restrict__ cnt) {
  __shared__ char lds[73728];          // 3 x (A 8KB + B 16KB)
  const int tid = threadIdx.x, l = tid & 63, w = tid >> 6;

  // bijective XCD-aware decode (r5-proven): combo fast, tok slow.
  const int lin = blockIdx.x;
  const int xcd = lin & 7, idx = lin >> 3;   // idx 0..399
  const int sub = idx % 25;
  const int bx  = idx / 25;                  // tok tile 0..15
  const int combo = xcd * 25 + sub;          // 0..199
  const int n  = combo % 50;
  const int dz = combo / 50;                 // 0..3
  const int tokbase = bx * 256;
  const int dbase   = dz * 128;

  const int wd = w >> 2, wt = w & 3;         // wave tile: 64 d x 64 tok
  f32x4 acc[4][4] = {};

  // staging: lane -> row l>>2, chunk l&3; source chunk pre-swizzled so the
  // LDS image carries chunk ^= ((row>>1)&3)   (conflict-free, r5/r6-proven)
  const int srow = l >> 2;
  const int schunk = ((l & 3) ^ ((l >> 3) & 3)) * 8;
  const bf16* aG = Wb  + ((size_t)(n * DLBL + dbase + w * 16 + srow)) * DLBL + schunk;
  const bf16* bG = sel + ((size_t)(tokbase + w * 32 + srow)) * DLBL + schunk;
  const int aOff = w * 1024;                 // w*16 rows * 64B
  const int bOff = 8192 + w * 2048;          // w*32 rows * 64B

  // frag reads: row = sub + lq, chunk = lh ^ ((lq>>1)&3)
  const int lq = l & 15, lh = l >> 4;
  const int ro = lh ^ ((lq >> 1) & 3);
  const char* rdA = lds + (wd * 64 + lq) * 64 + ro * 16;
  const char* rdB = lds + 8192 + (wt * 64 + lq) * 64 + ro * 16;

#define STG(T) do { \
    const bf16* a_ = aG + (T) * 32; \
    const bf16* b_ = bG + (T) * 32; \
    char* la_ = lds + ((T) % 3) * 24576 + aOff; \
    char* lb_ = lds + ((T) % 3) * 24576 + bOff; \
    gl16(a_, la_); \
    gl16(b_, lb_); \
    gl16(b_ + 16 * DLBL, lb_ + 1024); \
  } while (0)
#define WAITV(N) asm volatile("s_waitcnt vmcnt(" #N ")" ::: "memory")
#define PHASE(T, DOSTG, DOWV3, DOWV0, DOBAR) do { \
    if (DOSTG) STG((T) + 2); \
    const char* cA = rdA + ((T) % 3) * 24576; \
    const char* cB = rdB + ((T) % 3) * 24576; \
    bf16x8 aF[4], bF[4]; \
    aF[0] = *(const bf16x8*)(cA + 0 * 1024); \
    aF[1] = *(const bf16x8*)(cA + 1 * 1024); \
    aF[2] = *(const bf16x8*)(cA + 2 * 1024); \
    aF[3] = *(const bf16x8*)(cA + 3 * 1024); \
    bF[0] = *(const bf16x8*)(cB + 0 * 1024); \
    bF[1] = *(const bf16x8*)(cB + 1 * 1024); \
    bF[2] = *(const bf16x8*)(cB + 2 * 1024); \
    bF[3] = *(const bf16x8*)(cB + 3 * 1024); \
    __builtin_amdgcn_s_setprio(1); \
    _Pragma("unroll") \
    for (int i = 0; i < 4; ++i) \
      _Pragma("unroll") \
      for (int j = 0; j < 4; ++j) \
        acc[i][j] = __builtin_amdgcn_mfma_f32_16x16x32_bf16(aF[i], bF[j], acc[i][j], 0, 0, 0); \
    __builtin_amdgcn_s_setprio(0); \
    if (DOWV3) WAITV(3); \
    if (DOWV0) WAITV(0); \
    if (DOBAR) __builtin_amdgcn_s_barrier(); \
  } while (0)

  // prologue: stage tiles 0,1 (6 loads/wave); certify tile 0 (drain to 3)
  STG(0); STG(1);
  WAITV(3);
  __builtin_amdgcn_s_barrier();

  PHASE(0, 1, 1, 0, 1);  PHASE(1, 1, 1, 0, 1);  PHASE(2, 1, 1, 0, 1);
  PHASE(3, 1, 1, 0, 1);  PHASE(4, 1, 1, 0, 1);  PHASE(5, 1, 1, 0, 1);
  PHASE(6, 1, 1, 0, 1);  PHASE(7, 1, 1, 0, 1);  PHASE(8, 1, 1, 0, 1);
  PHASE(9, 1, 1, 0, 1);  PHASE(10, 1, 1, 0, 1); PHASE(11, 1, 1, 0, 1);
  PHASE(12, 1, 1, 0, 1); PHASE(13, 1, 1, 0, 1);
  PHASE(14, 0, 0, 1, 1);                      // no stage; certify tile 15
  PHASE(15, 0, 0, 0, 0);                      // final tile, no sync needed

#undef PHASE
#undef WAITV
#undef STG

  // ---- epilogue: H[d,t] * depT[d,t], reduce over the wave's 64 d ----
  float p[4] = {0.f, 0.f, 0.f, 0.f};
#pragma unroll
  for (int j = 0; j < 4; ++j) {
    const int tg = tokbase + wt * 64 + j * 16 + lq;
#pragma unroll
    for (int i = 0; i < 4; ++i)
#pragma unroll
      for (int r = 0; r < 4; ++r) {
        int dg = dbase + wd * 64 + i * 16 + lh * 4 + r;
        p[j] += acc[i][j][r] * (float)depT[(size_t)dg * NTOK + tg];
      }
  }
#pragma unroll
  for (int j = 0; j < 4; ++j) {
    p[j] += __shfl_xor(p[j], 16);
    p[j] += __shfl_xor(p[j], 32);
  }

  // cross-wd combine via LDS (K-loop done; LDS reusable after sync)
  __syncthreads();
  float* lf = (float*)lds;
  if (wd == 1 && l < 16) {
#pragma unroll
    for (int j = 0; j < 4; ++j) lf[(w - 4) * 64 + j * 16 + l] = p[j];
  }
  __syncthreads();
  if (wd == 0 && l < 16) {
#pragma unroll
    for (int j = 0; j < 4; ++j) {
      float v = p[j] + lf[w * 64 + j * 16 + l];
      int tg = tokbase + wt * 64 + j * 16 + l;
      parts[(size_t)dz * 204800 + (size_t)tg * NLAB + n] = v;
    }
  }

  // designated-reducer finish (threadFenceReduction pattern)
  __threadfence();
  __syncthreads();
  volatile int* flg = (int*)(lds + 2048);
  if (tid == 0) *flg = (atomicAdd(&cnt[n * 16 + bx], 1) == 3) ? 1 : 0;
  __syncthreads();
  if (*flg) {
    __threadfence();
    for (int i = tid; i < 256; i += 512) {
      const int tg = tokbase + i;
      float v = bias[n];
#pragma unroll
      for (int q = 0; q < 4; ++q) v += parts[(size_t)q * 204800 + (size_t)tg * NLAB + n];
      out[(size_t)tg * NLAB + n] = v;
    }
  }
}

// ---------------------------------------------------------------------------
extern "C" void kernel_launch(void* const* d_in, const int* in_sizes, int n_in,
                              void* d_out, int out_size, void* d_ws, size_t ws_size,
                              hipStream_t stream) {
  const float* dep    = (const float*)d_in[0];
  const float* head   = (const float*)d_in[1];
  const int*   hidx   = (const int*)d_in[2];
  const float* dep_W  = (const float*)d_in[4];
  const float* dep_b  = (const float*)d_in[5];
  const float* head_W = (const float*)d_in[6];
  const float* head_b = (const float*)d_in[7];
  const float* W      = (const float*)d_in[8];
  const float* bias   = (const float*)d_in[9];
  float* out = (float*)d_out;

  char* ws = (char*)d_ws;
  bf16*  Wb    = (bf16*)(ws);
  bf16*  depT  = (bf16*)(ws + 26214400);
  bf16*  selB  = (bf16*)(ws + 30408704);
  float* parts = (float*)(ws + 34603008);   // 4 * 204800 f32 = 3,276,800 B
  int*   cnt   = (int*)(ws + 37879808);     // 800 ints
  if (ws_size < (size_t)37883008) return;

  hipMemsetAsync(cnt, 0, 3200, stream);
  hipLaunchKernelGGL(prep_k, dim3(6912), dim3(256), 0, stream,
                     W, Wb, dep_W, dep, dep_b, depT, head, hidx, head_W, head_b, selB);
  hipLaunchKernelGGL(biaff_k, dim3(3200), dim3(512), 0, stream,
                     Wb, selB, depT, parts, bias, out, cnt);
}

// Round 10
// 1399.151 us; speedup vs baseline: 1.2395x; 1.2395x over previous
//
#include <hip/hip_runtime.h>
#include <hip/hip_bf16.h>
#include <cstdint>

typedef __bf16 bf16;
typedef bf16 bf16x8 __attribute__((ext_vector_type(8)));
typedef float f32x4 __attribute__((ext_vector_type(4)));

#define NTOK 4096   // B*T
#define DLBL 512    // D_LABEL
#define NLAB 50

__device__ inline bf16x8 cvt8(float4 a, float4 b) {
  bf16x8 r;
  r[0] = (bf16)a.x; r[1] = (bf16)a.y; r[2] = (bf16)a.z; r[3] = (bf16)a.w;
  r[4] = (bf16)b.x; r[5] = (bf16)b.y; r[6] = (bf16)b.z; r[7] = (bf16)b.w;
  return r;
}

// async global->LDS, 16B per lane; LDS dest = wave-uniform base + lane*16
__device__ __forceinline__ void gl16(const bf16* g, void* l) {
  __builtin_amdgcn_global_load_lds(
      (const __attribute__((address_space(1))) void*)g,
      (__attribute__((address_space(3))) void*)l, 16, 0, 0);
}

// ---------------------------------------------------------------------------
// Fused prep (r6-proven): blocks [0,256) projA (transposed out),
// [256,512) projB (gathered, natural out), [512,6912) convW.
// ---------------------------------------------------------------------------
__device__ void projA_body(int bidx, const float* __restrict__ Wp,
                           const float* __restrict__ X,
                           const float* __restrict__ bv,
                           bf16* __restrict__ outT, char* lds) {
  char* ldsA = lds;           // [128 e][32 d] bf16, row stride 80B
  char* ldsB = lds + 10240;   // [64 tok][32 d] bf16, row stride 80B
  const int tid = threadIdx.x, l = tid & 63, w = tid >> 6;
  const int tokbase = (bidx >> 2) * 64;
  const int ebase   = (bidx & 3) * 128;
  const int wr = w & 1, wc = w >> 1;
  f32x4 acc[4][2] = {};
  const int arow = tid >> 1, ahalf = tid & 1;
  const int brow = tid >> 2, bgr = tid & 3;
  const float* aS = Wp + (size_t)(ebase + arow) * 1024 + ahalf * 16;
  const float* bS = X  + (size_t)(tokbase + brow) * 1024 + bgr * 8;
  const int lo = (l & 15) * 80 + (l >> 4) * 16;
  for (int kb = 0; kb < 1024; kb += 32) {
    float4 a0 = *(const float4*)(aS + kb);
    float4 a1 = *(const float4*)(aS + kb + 4);
    float4 a2 = *(const float4*)(aS + kb + 8);
    float4 a3 = *(const float4*)(aS + kb + 12);
    float4 b0 = *(const float4*)(bS + kb);
    float4 b1 = *(const float4*)(bS + kb + 4);
    *(bf16x8*)(ldsA + arow * 80 + ahalf * 32)      = cvt8(a0, a1);
    *(bf16x8*)(ldsA + arow * 80 + ahalf * 32 + 16) = cvt8(a2, a3);
    *(bf16x8*)(ldsB + brow * 80 + bgr * 16)        = cvt8(b0, b1);
    __syncthreads();
    bf16x8 aF[4], bF[2];
#pragma unroll
    for (int i = 0; i < 4; ++i) aF[i] = *(bf16x8*)(ldsA + (wr * 64 + i * 16) * 80 + lo);
#pragma unroll
    for (int j = 0; j < 2; ++j) bF[j] = *(bf16x8*)(ldsB + (wc * 32 + j * 16) * 80 + lo);
#pragma unroll
    for (int i = 0; i < 4; ++i)
#pragma unroll
      for (int j = 0; j < 2; ++j)
        acc[i][j] = __builtin_amdgcn_mfma_f32_16x16x32_bf16(aF[i], bF[j], acc[i][j], 0, 0, 0);
    __syncthreads();
  }
#pragma unroll
  for (int i = 0; i < 4; ++i)
#pragma unroll
    for (int j = 0; j < 2; ++j)
#pragma unroll
      for (int r = 0; r < 4; ++r) {
        int eg = ebase + wr * 64 + i * 16 + (l >> 4) * 4 + r;
        int tg = tokbase + wc * 32 + j * 16 + (l & 15);
        outT[(size_t)eg * NTOK + tg] = (bf16)(acc[i][j][r] + bv[eg]);
      }
}

__device__ void projB_body(int bidx, const float* __restrict__ head,
                           const int* __restrict__ hidx,
                           const float* __restrict__ Wp,
                           const float* __restrict__ bv,
                           bf16* __restrict__ selO, char* lds) {
  char* ldsA = lds;           // [128 tok][32 d], stride 80
  char* ldsB = lds + 10240;   // [64 e][32 d], stride 80
  const int tid = threadIdx.x, l = tid & 63, w = tid >> 6;
  const int tokbase = (bidx >> 3) * 128;
  const int ebase   = (bidx & 7) * 64;
  const int wr = w & 1, wc = w >> 1;
  f32x4 acc[4][2] = {};
  const int arow = tid >> 1, ahalf = tid & 1;
  const int brow = tid >> 2, bgr = tid & 3;
  const int flat = tokbase + arow;
  const int bb = flat >> 11;
  const int hv = hidx[flat];
  const float* aS = head + ((size_t)bb * 2049 + hv) * 1024 + ahalf * 16;
  const float* bS = Wp + (size_t)(ebase + brow) * 1024 + bgr * 8;
  const int lo = (l & 15) * 80 + (l >> 4) * 16;
  for (int kb = 0; kb < 1024; kb += 32) {
    float4 a0 = *(const float4*)(aS + kb);
    float4 a1 = *(const float4*)(aS + kb + 4);
    float4 a2 = *(const float4*)(aS + kb + 8);
    float4 a3 = *(const float4*)(aS + kb + 12);
    float4 b0 = *(const float4*)(bS + kb);
    float4 b1 = *(const float4*)(bS + kb + 4);
    *(bf16x8*)(ldsA + arow * 80 + ahalf * 32)      = cvt8(a0, a1);
    *(bf16x8*)(ldsA + arow * 80 + ahalf * 32 + 16) = cvt8(a2, a3);
    *(bf16x8*)(ldsB + brow * 80 + bgr * 16)        = cvt8(b0, b1);
    __syncthreads();
    bf16x8 aF[4], bF[2];
#pragma unroll
    for (int i = 0; i < 4; ++i) aF[i] = *(bf16x8*)(ldsA + (wr * 64 + i * 16) * 80 + lo);
#pragma unroll
    for (int j = 0; j < 2; ++j) bF[j] = *(bf16x8*)(ldsB + (wc * 32 + j * 16) * 80 + lo);
#pragma unroll
    for (int i = 0; i < 4; ++i)
#pragma unroll
      for (int j = 0; j < 2; ++j)
        acc[i][j] = __builtin_amdgcn_mfma_f32_16x16x32_bf16(aF[i], bF[j], acc[i][j], 0, 0, 0);
    __syncthreads();
  }
#pragma unroll
  for (int i = 0; i < 4; ++i)
#pragma unroll
    for (int j = 0; j < 2; ++j)
#pragma unroll
      for (int r = 0; r < 4; ++r) {
        int tg = tokbase + wr * 64 + i * 16 + (l >> 4) * 4 + r;
        int eg = ebase + wc * 32 + j * 16 + (l & 15);
        selO[(size_t)tg * DLBL + eg] = (bf16)(acc[i][j][r] + bv[eg]);
      }
}

__global__ __launch_bounds__(256) void prep_k(const float* __restrict__ W,
                                              bf16* __restrict__ Wb,
                                              const float* __restrict__ dep_W,
                                              const float* __restrict__ dep,
                                              const float* __restrict__ dep_b,
                                              bf16* __restrict__ depT,
                                              const float* __restrict__ head,
                                              const int* __restrict__ hidx,
                                              const float* __restrict__ head_W,
                                              const float* __restrict__ head_b,
                                              bf16* __restrict__ selB) {
  __shared__ char lds[15360];
  const int b = blockIdx.x;
  if (b < 256) {
    projA_body(b, dep_W, dep, dep_b, depT, lds);
  } else if (b < 512) {
    projB_body(b - 256, head, hidx, head_W, head_b, selB, lds);
  } else {
    int i = (b - 512) * 256 + threadIdx.x;
    const float4* s = (const float4*)W + (size_t)i * 2;
    float4 a = s[0], c = s[1];
    *(bf16x8*)(Wb + (size_t)i * 8) = cvt8(a, c);
  }
}

// ---------------------------------------------------------------------------
// Kernel 4 v10: r5's proven K-loop EXACTLY (ds_read FIRST, then STG, then
// MFMA — ds_read must precede global_load_lds in program order or the
// compiler inserts vmcnt(0) before the reads due to LDS aliasing; r9's
// STAGE-first variant was 13x slower for this reason). Epilogue: cross-wd
// LDS combine -> 4 parts slices + designated-reducer finish (no fin_k).
// ---------------------------------------------------------------------------
__global__ __launch_bounds__(512, 2) void biaff_k(const bf16* __restrict__ Wb,
                                                  const bf16* __restrict__ sel,
                                                  const bf16* __restrict__ depT,
                                                  float* __restrict__ parts,
                                                  const float* __restrict__ bias,
                                                  float* __restrict__ out,
                                                  int* __restrict__ cnt) {
  __shared__ char lds[73728];          // 3 x (A 8KB + B 16KB)
  const int tid = threadIdx.x, l = tid & 63, w = tid >> 6;

  // bijective XCD-aware decode (r5-proven): combo fast, tok slow.
  const int lin = blockIdx.x;
  const int xcd = lin & 7, idx = lin >> 3;   // idx 0..399
  const int sub = idx % 25;
  const int bx  = idx / 25;                  // tok tile 0..15
  const int combo = xcd * 25 + sub;          // 0..199
  const int n  = combo % 50;
  const int dz = combo / 50;                 // 0..3
  const int tokbase = bx * 256;
  const int dbase   = dz * 128;

  const int wd = w >> 2, wt = w & 3;         // wave tile: 64 d x 64 tok
  f32x4 acc[4][4] = {};

  // staging: lane -> row l>>2, chunk l&3; source chunk pre-swizzled so the
  // LDS image carries chunk ^= ((row>>1)&3)   (conflict-free, r5/r6-proven)
  const int srow = l >> 2;
  const int schunk = ((l & 3) ^ ((l >> 3) & 3)) * 8;
  const bf16* aG = Wb  + ((size_t)(n * DLBL + dbase + w * 16 + srow)) * DLBL + schunk;
  const bf16* bG = sel + ((size_t)(tokbase + w * 32 + srow)) * DLBL + schunk;
  const int aOff = w * 1024;                 // w*16 rows * 64B
  const int bOff = 8192 + w * 2048;          // w*32 rows * 64B

  // frag reads: row = sub + lq, chunk = lh ^ ((lq>>1)&3)
  const int lq = l & 15, lh = l >> 4;
  const int ro = lh ^ ((lq >> 1) & 3);
  const char* rdA = lds + (wd * 64 + lq) * 64 + ro * 16;
  const char* rdB = lds + 8192 + (wt * 64 + lq) * 64 + ro * 16;

#define STG(T) do { \
    const bf16* a_ = aG + (T) * 32; \
    const bf16* b_ = bG + (T) * 32; \
    char* la_ = lds + ((T) % 3) * 24576 + aOff; \
    char* lb_ = lds + ((T) % 3) * 24576 + bOff; \
    gl16(a_, la_); \
    gl16(b_, lb_); \
    gl16(b_ + 16 * DLBL, lb_ + 1024); \
  } while (0)
#define WAITV(N) asm volatile("s_waitcnt vmcnt(" #N ")" ::: "memory")
#define PHASE(T, DOSTG, DOWV3, DOWV0, DOBAR) do { \
    const char* cA = rdA + ((T) % 3) * 24576; \
    const char* cB = rdB + ((T) % 3) * 24576; \
    bf16x8 aF[4], bF[4]; \
    aF[0] = *(const bf16x8*)(cA + 0 * 1024); \
    aF[1] = *(const bf16x8*)(cA + 1 * 1024); \
    aF[2] = *(const bf16x8*)(cA + 2 * 1024); \
    aF[3] = *(const bf16x8*)(cA + 3 * 1024); \
    bF[0] = *(const bf16x8*)(cB + 0 * 1024); \
    bF[1] = *(const bf16x8*)(cB + 1 * 1024); \
    bF[2] = *(const bf16x8*)(cB + 2 * 1024); \
    bF[3] = *(const bf16x8*)(cB + 3 * 1024); \
    if (DOSTG) STG((T) + 2); \
    __builtin_amdgcn_s_setprio(1); \
    _Pragma("unroll") \
    for (int i = 0; i < 4; ++i) \
      _Pragma("unroll") \
      for (int j = 0; j < 4; ++j) \
        acc[i][j] = __builtin_amdgcn_mfma_f32_16x16x32_bf16(aF[i], bF[j], acc[i][j], 0, 0, 0); \
    __builtin_amdgcn_s_setprio(0); \
    if (DOWV3) WAITV(3); \
    if (DOWV0) WAITV(0); \
    if (DOBAR) __builtin_amdgcn_s_barrier(); \
  } while (0)

  // prologue: stage tiles 0,1 (6 loads/wave); certify tile 0 (drain to 3)
  STG(0); STG(1);
  WAITV(3);
  __builtin_amdgcn_s_barrier();

  PHASE(0, 1, 1, 0, 1);  PHASE(1, 1, 1, 0, 1);  PHASE(2, 1, 1, 0, 1);
  PHASE(3, 1, 1, 0, 1);  PHASE(4, 1, 1, 0, 1);  PHASE(5, 1, 1, 0, 1);
  PHASE(6, 1, 1, 0, 1);  PHASE(7, 1, 1, 0, 1);  PHASE(8, 1, 1, 0, 1);
  PHASE(9, 1, 1, 0, 1);  PHASE(10, 1, 1, 0, 1); PHASE(11, 1, 1, 0, 1);
  PHASE(12, 1, 1, 0, 1); PHASE(13, 1, 1, 0, 1);
  PHASE(14, 0, 0, 1, 1);                      // no stage; certify tile 15
  PHASE(15, 0, 0, 0, 0);                      // final tile, no sync needed

#undef PHASE
#undef WAITV
#undef STG

  // ---- epilogue: H[d,t] * depT[d,t], reduce over the wave's 64 d ----
  float p[4] = {0.f, 0.f, 0.f, 0.f};
#pragma unroll
  for (int j = 0; j < 4; ++j) {
    const int tg = tokbase + wt * 64 + j * 16 + lq;
#pragma unroll
    for (int i = 0; i < 4; ++i)
#pragma unroll
      for (int r = 0; r < 4; ++r) {
        int dg = dbase + wd * 64 + i * 16 + lh * 4 + r;
        p[j] += acc[i][j][r] * (float)depT[(size_t)dg * NTOK + tg];
      }
  }
#pragma unroll
  for (int j = 0; j < 4; ++j) {
    p[j] += __shfl_xor(p[j], 16);
    p[j] += __shfl_xor(p[j], 32);
  }

  // cross-wd combine via LDS (K-loop done; LDS reusable after sync)
  __syncthreads();
  float* lf = (float*)lds;
  if (wd == 1 && l < 16) {
#pragma unroll
    for (int j = 0; j < 4; ++j) lf[(w - 4) * 64 + j * 16 + l] = p[j];
  }
  __syncthreads();
  if (wd == 0 && l < 16) {
#pragma unroll
    for (int j = 0; j < 4; ++j) {
      float v = p[j] + lf[w * 64 + j * 16 + l];
      int tg = tokbase + wt * 64 + j * 16 + l;
      parts[(size_t)dz * 204800 + (size_t)tg * NLAB + n] = v;
    }
  }

  // designated-reducer finish (threadFenceReduction pattern)
  __threadfence();
  __syncthreads();
  volatile int* flg = (int*)(lds + 2048);
  if (tid == 0) *flg = (atomicAdd(&cnt[n * 16 + bx], 1) == 3) ? 1 : 0;
  __syncthreads();
  if (*flg) {
    __threadfence();
    for (int i = tid; i < 256; i += 512) {
      const int tg = tokbase + i;
      float v = bias[n];
#pragma unroll
      for (int q = 0; q < 4; ++q) v += parts[(size_t)q * 204800 + (size_t)tg * NLAB + n];
      out[(size_t)tg * NLAB + n] = v;
    }
  }
}

// ---------------------------------------------------------------------------
extern "C" void kernel_launch(void* const* d_in, const int* in_sizes, int n_in,
                              void* d_out, int out_size, void* d_ws, size_t ws_size,
                              hipStream_t stream) {
  const float* dep    = (const float*)d_in[0];
  const float* head   = (const float*)d_in[1];
  const int*   hidx   = (const int*)d_in[2];
  const float* dep_W  = (const float*)d_in[4];
  const float* dep_b  = (const float*)d_in[5];
  const float* head_W = (const float*)d_in[6];
  const float* head_b = (const float*)d_in[7];
  const float* W      = (const float*)d_in[8];
  const float* bias   = (const float*)d_in[9];
  float* out = (float*)d_out;

  char* ws = (char*)d_ws;
  bf16*  Wb    = (bf16*)(ws);
  bf16*  depT  = (bf16*)(ws + 26214400);
  bf16*  selB  = (bf16*)(ws + 30408704);
  float* parts = (float*)(ws + 34603008);   // 4 * 204800 f32 = 3,276,800 B
  int*   cnt   = (int*)(ws + 37879808);     // 800 ints
  if (ws_size < (size_t)37883008) return;

  hipMemsetAsync(cnt, 0, 3200, stream);
  hipLaunchKernelGGL(prep_k, dim3(6912), dim3(256), 0, stream,
                     W, Wb, dep_W, dep, dep_b, depT, head, hidx, head_W, head_b, selB);
  hipLaunchKernelGGL(biaff_k, dim3(3200), dim3(512), 0, stream,
                     Wb, selB, depT, parts, bias, out, cnt);
}

// Round 11
// 172.152 us; speedup vs baseline: 10.0737x; 8.1274x over previous
//
#include <hip/hip_runtime.h>
#include <hip/hip_bf16.h>
#include <cstdint>

typedef __bf16 bf16;
typedef bf16 bf16x8 __attribute__((ext_vector_type(8)));
typedef float f32x4 __attribute__((ext_vector_type(4)));

#define NTOK 4096   // B*T
#define DLBL 512    // D_LABEL
#define NLAB 50

__device__ inline bf16x8 cvt8(float4 a, float4 b) {
  bf16x8 r;
  r[0] = (bf16)a.x; r[1] = (bf16)a.y; r[2] = (bf16)a.z; r[3] = (bf16)a.w;
  r[4] = (bf16)b.x; r[5] = (bf16)b.y; r[6] = (bf16)b.z; r[7] = (bf16)b.w;
  return r;
}

// async global->LDS, 16B per lane; LDS dest = wave-uniform base + lane*16
__device__ __forceinline__ void gl16(const bf16* g, void* l) {
  __builtin_amdgcn_global_load_lds(
      (const __attribute__((address_space(1))) void*)g,
      (__attribute__((address_space(3))) void*)l, 16, 0, 0);
}

// ---------------------------------------------------------------------------
// Fused prep (r6-proven): blocks [0,256) projA (transposed out),
// [256,512) projB (gathered, natural out), [512,6912) convW.
// ---------------------------------------------------------------------------
__device__ void projA_body(int bidx, const float* __restrict__ Wp,
                           const float* __restrict__ X,
                           const float* __restrict__ bv,
                           bf16* __restrict__ outT, char* lds) {
  char* ldsA = lds;           // [128 e][32 d] bf16, row stride 80B
  char* ldsB = lds + 10240;   // [64 tok][32 d] bf16, row stride 80B
  const int tid = threadIdx.x, l = tid & 63, w = tid >> 6;
  const int tokbase = (bidx >> 2) * 64;
  const int ebase   = (bidx & 3) * 128;
  const int wr = w & 1, wc = w >> 1;
  f32x4 acc[4][2] = {};
  const int arow = tid >> 1, ahalf = tid & 1;
  const int brow = tid >> 2, bgr = tid & 3;
  const float* aS = Wp + (size_t)(ebase + arow) * 1024 + ahalf * 16;
  const float* bS = X  + (size_t)(tokbase + brow) * 1024 + bgr * 8;
  const int lo = (l & 15) * 80 + (l >> 4) * 16;
  for (int kb = 0; kb < 1024; kb += 32) {
    float4 a0 = *(const float4*)(aS + kb);
    float4 a1 = *(const float4*)(aS + kb + 4);
    float4 a2 = *(const float4*)(aS + kb + 8);
    float4 a3 = *(const float4*)(aS + kb + 12);
    float4 b0 = *(const float4*)(bS + kb);
    float4 b1 = *(const float4*)(bS + kb + 4);
    *(bf16x8*)(ldsA + arow * 80 + ahalf * 32)      = cvt8(a0, a1);
    *(bf16x8*)(ldsA + arow * 80 + ahalf * 32 + 16) = cvt8(a2, a3);
    *(bf16x8*)(ldsB + brow * 80 + bgr * 16)        = cvt8(b0, b1);
    __syncthreads();
    bf16x8 aF[4], bF[2];
#pragma unroll
    for (int i = 0; i < 4; ++i) aF[i] = *(bf16x8*)(ldsA + (wr * 64 + i * 16) * 80 + lo);
#pragma unroll
    for (int j = 0; j < 2; ++j) bF[j] = *(bf16x8*)(ldsB + (wc * 32 + j * 16) * 80 + lo);
#pragma unroll
    for (int i = 0; i < 4; ++i)
#pragma unroll
      for (int j = 0; j < 2; ++j)
        acc[i][j] = __builtin_amdgcn_mfma_f32_16x16x32_bf16(aF[i], bF[j], acc[i][j], 0, 0, 0);
    __syncthreads();
  }
#pragma unroll
  for (int i = 0; i < 4; ++i)
#pragma unroll
    for (int j = 0; j < 2; ++j)
#pragma unroll
      for (int r = 0; r < 4; ++r) {
        int eg = ebase + wr * 64 + i * 16 + (l >> 4) * 4 + r;
        int tg = tokbase + wc * 32 + j * 16 + (l & 15);
        outT[(size_t)eg * NTOK + tg] = (bf16)(acc[i][j][r] + bv[eg]);
      }
}

__device__ void projB_body(int bidx, const float* __restrict__ head,
                           const int* __restrict__ hidx,
                           const float* __restrict__ Wp,
                           const float* __restrict__ bv,
                           bf16* __restrict__ selO, char* lds) {
  char* ldsA = lds;           // [128 tok][32 d], stride 80
  char* ldsB = lds + 10240;   // [64 e][32 d], stride 80
  const int tid = threadIdx.x, l = tid & 63, w = tid >> 6;
  const int tokbase = (bidx >> 3) * 128;
  const int ebase   = (bidx & 7) * 64;
  const int wr = w & 1, wc = w >> 1;
  f32x4 acc[4][2] = {};
  const int arow = tid >> 1, ahalf = tid & 1;
  const int brow = tid >> 2, bgr = tid & 3;
  const int flat = tokbase + arow;
  const int bb = flat >> 11;
  const int hv = hidx[flat];
  const float* aS = head + ((size_t)bb * 2049 + hv) * 1024 + ahalf * 16;
  const float* bS = Wp + (size_t)(ebase + brow) * 1024 + bgr * 8;
  const int lo = (l & 15) * 80 + (l >> 4) * 16;
  for (int kb = 0; kb < 1024; kb += 32) {
    float4 a0 = *(const float4*)(aS + kb);
    float4 a1 = *(const float4*)(aS + kb + 4);
    float4 a2 = *(const float4*)(aS + kb + 8);
    float4 a3 = *(const float4*)(aS + kb + 12);
    float4 b0 = *(const float4*)(bS + kb);
    float4 b1 = *(const float4*)(bS + kb + 4);
    *(bf16x8*)(ldsA + arow * 80 + ahalf * 32)      = cvt8(a0, a1);
    *(bf16x8*)(ldsA + arow * 80 + ahalf * 32 + 16) = cvt8(a2, a3);
    *(bf16x8*)(ldsB + brow * 80 + bgr * 16)        = cvt8(b0, b1);
    __syncthreads();
    bf16x8 aF[4], bF[2];
#pragma unroll
    for (int i = 0; i < 4; ++i) aF[i] = *(bf16x8*)(ldsA + (wr * 64 + i * 16) * 80 + lo);
#pragma unroll
    for (int j = 0; j < 2; ++j) bF[j] = *(bf16x8*)(ldsB + (wc * 32 + j * 16) * 80 + lo);
#pragma unroll
    for (int i = 0; i < 4; ++i)
#pragma unroll
      for (int j = 0; j < 2; ++j)
        acc[i][j] = __builtin_amdgcn_mfma_f32_16x16x32_bf16(aF[i], bF[j], acc[i][j], 0, 0, 0);
    __syncthreads();
  }
#pragma unroll
  for (int i = 0; i < 4; ++i)
#pragma unroll
    for (int j = 0; j < 2; ++j)
#pragma unroll
      for (int r = 0; r < 4; ++r) {
        int tg = tokbase + wr * 64 + i * 16 + (l >> 4) * 4 + r;
        int eg = ebase + wc * 32 + j * 16 + (l & 15);
        selO[(size_t)tg * DLBL + eg] = (bf16)(acc[i][j][r] + bv[eg]);
      }
}

__global__ __launch_bounds__(256) void prep_k(const float* __restrict__ W,
                                              bf16* __restrict__ Wb,
                                              const float* __restrict__ dep_W,
                                              const float* __restrict__ dep,
                                              const float* __restrict__ dep_b,
                                              bf16* __restrict__ depT,
                                              const float* __restrict__ head,
                                              const int* __restrict__ hidx,
                                              const float* __restrict__ head_W,
                                              const float* __restrict__ head_b,
                                              bf16* __restrict__ selB) {
  __shared__ char lds[15360];
  const int b = blockIdx.x;
  if (b < 256) {
    projA_body(b, dep_W, dep, dep_b, depT, lds);
  } else if (b < 512) {
    projB_body(b - 256, head, hidx, head_W, head_b, selB, lds);
  } else {
    int i = (b - 512) * 256 + threadIdx.x;
    const float4* s = (const float4*)W + (size_t)i * 2;
    float4 a = s[0], c = s[1];
    *(bf16x8*)(Wb + (size_t)i * 8) = cvt8(a, c);
  }
}

// ---------------------------------------------------------------------------
// Kernel 4 v11: r5's proven K-loop EXACTLY (125.8us measured). Epilogue adds
// only the benign cross-wd LDS combine (pure LDS + syncthreads) -> 4 parts
// slices. NO __threadfence / atomics here: device-scope fences emit L2
// invalidations that destroyed L2 reuse for in-flight blocks (r9/r10: 13x).
// Separate fin_k does the final 4-way sum + bias.
// ---------------------------------------------------------------------------
__global__ __launch_bounds__(512, 2) void biaff_k(const bf16* __restrict__ Wb,
                                                  const bf16* __restrict__ sel,
                                                  const bf16* __restrict__ depT,
                                                  float* __restrict__ parts) {
  __shared__ char lds[73728];          // 3 x (A 8KB + B 16KB)
  const int tid = threadIdx.x, l = tid & 63, w = tid >> 6;

  // bijective XCD-aware decode (r5-proven): combo fast, tok slow.
  const int lin = blockIdx.x;
  const int xcd = lin & 7, idx = lin >> 3;   // idx 0..399
  const int sub = idx % 25;
  const int bx  = idx / 25;                  // tok tile 0..15
  const int combo = xcd * 25 + sub;          // 0..199
  const int n  = combo % 50;
  const int dz = combo / 50;                 // 0..3
  const int tokbase = bx * 256;
  const int dbase   = dz * 128;

  const int wd = w >> 2, wt = w & 3;         // wave tile: 64 d x 64 tok
  f32x4 acc[4][4] = {};

  // staging: lane -> row l>>2, chunk l&3; source chunk pre-swizzled so the
  // LDS image carries chunk ^= ((row>>1)&3)   (conflict-free, r5/r6-proven)
  const int srow = l >> 2;
  const int schunk = ((l & 3) ^ ((l >> 3) & 3)) * 8;
  const bf16* aG = Wb  + ((size_t)(n * DLBL + dbase + w * 16 + srow)) * DLBL + schunk;
  const bf16* bG = sel + ((size_t)(tokbase + w * 32 + srow)) * DLBL + schunk;
  const int aOff = w * 1024;                 // w*16 rows * 64B
  const int bOff = 8192 + w * 2048;          // w*32 rows * 64B

  // frag reads: row = sub + lq, chunk = lh ^ ((lq>>1)&3)
  const int lq = l & 15, lh = l >> 4;
  const int ro = lh ^ ((lq >> 1) & 3);
  const char* rdA = lds + (wd * 64 + lq) * 64 + ro * 16;
  const char* rdB = lds + 8192 + (wt * 64 + lq) * 64 + ro * 16;

#define STG(T) do { \
    const bf16* a_ = aG + (T) * 32; \
    const bf16* b_ = bG + (T) * 32; \
    char* la_ = lds + ((T) % 3) * 24576 + aOff; \
    char* lb_ = lds + ((T) % 3) * 24576 + bOff; \
    gl16(a_, la_); \
    gl16(b_, lb_); \
    gl16(b_ + 16 * DLBL, lb_ + 1024); \
  } while (0)
#define WAITV(N) asm volatile("s_waitcnt vmcnt(" #N ")" ::: "memory")
#define PHASE(T, DOSTG, DOWV3, DOWV0, DOBAR) do { \
    const char* cA = rdA + ((T) % 3) * 24576; \
    const char* cB = rdB + ((T) % 3) * 24576; \
    bf16x8 aF[4], bF[4]; \
    aF[0] = *(const bf16x8*)(cA + 0 * 1024); \
    aF[1] = *(const bf16x8*)(cA + 1 * 1024); \
    aF[2] = *(const bf16x8*)(cA + 2 * 1024); \
    aF[3] = *(const bf16x8*)(cA + 3 * 1024); \
    bF[0] = *(const bf16x8*)(cB + 0 * 1024); \
    bF[1] = *(const bf16x8*)(cB + 1 * 1024); \
    bF[2] = *(const bf16x8*)(cB + 2 * 1024); \
    bF[3] = *(const bf16x8*)(cB + 3 * 1024); \
    if (DOSTG) STG((T) + 2); \
    __builtin_amdgcn_s_setprio(1); \
    _Pragma("unroll") \
    for (int i = 0; i < 4; ++i) \
      _Pragma("unroll") \
      for (int j = 0; j < 4; ++j) \
        acc[i][j] = __builtin_amdgcn_mfma_f32_16x16x32_bf16(aF[i], bF[j], acc[i][j], 0, 0, 0); \
    __builtin_amdgcn_s_setprio(0); \
    if (DOWV3) WAITV(3); \
    if (DOWV0) WAITV(0); \
    if (DOBAR) __builtin_amdgcn_s_barrier(); \
  } while (0)

  // prologue: stage tiles 0,1 (6 loads/wave); certify tile 0 (drain to 3)
  STG(0); STG(1);
  WAITV(3);
  __builtin_amdgcn_s_barrier();

  PHASE(0, 1, 1, 0, 1);  PHASE(1, 1, 1, 0, 1);  PHASE(2, 1, 1, 0, 1);
  PHASE(3, 1, 1, 0, 1);  PHASE(4, 1, 1, 0, 1);  PHASE(5, 1, 1, 0, 1);
  PHASE(6, 1, 1, 0, 1);  PHASE(7, 1, 1, 0, 1);  PHASE(8, 1, 1, 0, 1);
  PHASE(9, 1, 1, 0, 1);  PHASE(10, 1, 1, 0, 1); PHASE(11, 1, 1, 0, 1);
  PHASE(12, 1, 1, 0, 1); PHASE(13, 1, 1, 0, 1);
  PHASE(14, 0, 0, 1, 1);                      // no stage; certify tile 15
  PHASE(15, 0, 0, 0, 0);                      // final tile, no sync needed

#undef PHASE
#undef WAITV
#undef STG

  // ---- epilogue: H[d,t] * depT[d,t], reduce over the wave's 64 d ----
  float p[4] = {0.f, 0.f, 0.f, 0.f};
#pragma unroll
  for (int j = 0; j < 4; ++j) {
    const int tg = tokbase + wt * 64 + j * 16 + lq;
#pragma unroll
    for (int i = 0; i < 4; ++i)
#pragma unroll
      for (int r = 0; r < 4; ++r) {
        int dg = dbase + wd * 64 + i * 16 + lh * 4 + r;
        p[j] += acc[i][j][r] * (float)depT[(size_t)dg * NTOK + tg];
      }
  }
#pragma unroll
  for (int j = 0; j < 4; ++j) {
    p[j] += __shfl_xor(p[j], 16);
    p[j] += __shfl_xor(p[j], 32);
  }

  // cross-wd combine via LDS (K-loop done; LDS reusable after sync)
  __syncthreads();
  float* lf = (float*)lds;
  if (wd == 1 && l < 16) {
#pragma unroll
    for (int j = 0; j < 4; ++j) lf[(w - 4) * 64 + j * 16 + l] = p[j];
  }
  __syncthreads();
  if (wd == 0 && l < 16) {
#pragma unroll
    for (int j = 0; j < 4; ++j) {
      float v = p[j] + lf[w * 64 + j * 16 + l];
      int tg = tokbase + wt * 64 + j * 16 + l;
      parts[(size_t)dz * 204800 + (size_t)tg * NLAB + n] = v;
    }
  }
}

// ---------------------------------------------------------------------------
// Kernel 5: sum the 4 dz-partials + bias -> logits [4096][50] f32
// ---------------------------------------------------------------------------
__global__ __launch_bounds__(256) void fin_k(const float* __restrict__ parts,
                                             const float* __restrict__ bias,
                                             float* __restrict__ out) {
  int i = blockIdx.x * 256 + threadIdx.x;
  float v = 0.f;
#pragma unroll
  for (int q = 0; q < 4; ++q) v += parts[(size_t)q * 204800 + i];
  out[i] = v + bias[i % NLAB];
}

// ---------------------------------------------------------------------------
extern "C" void kernel_launch(void* const* d_in, const int* in_sizes, int n_in,
                              void* d_out, int out_size, void* d_ws, size_t ws_size,
                              hipStream_t stream) {
  const float* dep    = (const float*)d_in[0];
  const float* head   = (const float*)d_in[1];
  const int*   hidx   = (const int*)d_in[2];
  const float* dep_W  = (const float*)d_in[4];
  const float* dep_b  = (const float*)d_in[5];
  const float* head_W = (const float*)d_in[6];
  const float* head_b = (const float*)d_in[7];
  const float* W      = (const float*)d_in[8];
  const float* bias   = (const float*)d_in[9];
  float* out = (float*)d_out;

  char* ws = (char*)d_ws;
  bf16*  Wb    = (bf16*)(ws);
  bf16*  depT  = (bf16*)(ws + 26214400);
  bf16*  selB  = (bf16*)(ws + 30408704);
  float* parts = (float*)(ws + 34603008);   // 4 * 204800 f32 = 3,276,800 B
  if (ws_size < (size_t)37879808) return;

  hipLaunchKernelGGL(prep_k, dim3(6912), dim3(256), 0, stream,
                     W, Wb, dep_W, dep, dep_b, depT, head, hidx, head_W, head_b, selB);
  hipLaunchKernelGGL(biaff_k, dim3(3200), dim3(512), 0, stream,
                     Wb, selB, depT, parts);
  hipLaunchKernelGGL(fin_k, dim3(800), dim3(256), 0, stream, parts, bias, out);
}

// Round 12
// 163.969 us; speedup vs baseline: 10.5764x; 1.0499x over previous
//
#include <hip/hip_runtime.h>
#include <hip/hip_bf16.h>
#include <cstdint>

typedef __bf16 bf16;
typedef bf16 bf16x8 __attribute__((ext_vector_type(8)));
typedef float f32x4 __attribute__((ext_vector_type(4)));

#define NTOK 4096   // B*T
#define DLBL 512    // D_LABEL
#define NLAB 50

__device__ inline bf16x8 cvt8(float4 a, float4 b) {
  bf16x8 r;
  r[0] = (bf16)a.x; r[1] = (bf16)a.y; r[2] = (bf16)a.z; r[3] = (bf16)a.w;
  r[4] = (bf16)b.x; r[5] = (bf16)b.y; r[6] = (bf16)b.z; r[7] = (bf16)b.w;
  return r;
}

// async global->LDS, 16B per lane; LDS dest = wave-uniform base + lane*16
__device__ __forceinline__ void gl16(const bf16* g, void* l) {
  __builtin_amdgcn_global_load_lds(
      (const __attribute__((address_space(1))) void*)g,
      (__attribute__((address_space(3))) void*)l, 16, 0, 0);
}

// ---------------------------------------------------------------------------
// Fused prep (r6-proven): blocks [0,256) projA (transposed out),
// [256,512) projB (gathered, natural out), [512,6912) convW.
// ---------------------------------------------------------------------------
__device__ void projA_body(int bidx, const float* __restrict__ Wp,
                           const float* __restrict__ X,
                           const float* __restrict__ bv,
                           bf16* __restrict__ outT, char* lds) {
  char* ldsA = lds;           // [128 e][32 d] bf16, row stride 80B
  char* ldsB = lds + 10240;   // [64 tok][32 d] bf16, row stride 80B
  const int tid = threadIdx.x, l = tid & 63, w = tid >> 6;
  const int tokbase = (bidx >> 2) * 64;
  const int ebase   = (bidx & 3) * 128;
  const int wr = w & 1, wc = w >> 1;
  f32x4 acc[4][2] = {};
  const int arow = tid >> 1, ahalf = tid & 1;
  const int brow = tid >> 2, bgr = tid & 3;
  const float* aS = Wp + (size_t)(ebase + arow) * 1024 + ahalf * 16;
  const float* bS = X  + (size_t)(tokbase + brow) * 1024 + bgr * 8;
  const int lo = (l & 15) * 80 + (l >> 4) * 16;
  for (int kb = 0; kb < 1024; kb += 32) {
    float4 a0 = *(const float4*)(aS + kb);
    float4 a1 = *(const float4*)(aS + kb + 4);
    float4 a2 = *(const float4*)(aS + kb + 8);
    float4 a3 = *(const float4*)(aS + kb + 12);
    float4 b0 = *(const float4*)(bS + kb);
    float4 b1 = *(const float4*)(bS + kb + 4);
    *(bf16x8*)(ldsA + arow * 80 + ahalf * 32)      = cvt8(a0, a1);
    *(bf16x8*)(ldsA + arow * 80 + ahalf * 32 + 16) = cvt8(a2, a3);
    *(bf16x8*)(ldsB + brow * 80 + bgr * 16)        = cvt8(b0, b1);
    __syncthreads();
    bf16x8 aF[4], bF[2];
#pragma unroll
    for (int i = 0; i < 4; ++i) aF[i] = *(bf16x8*)(ldsA + (wr * 64 + i * 16) * 80 + lo);
#pragma unroll
    for (int j = 0; j < 2; ++j) bF[j] = *(bf16x8*)(ldsB + (wc * 32 + j * 16) * 80 + lo);
#pragma unroll
    for (int i = 0; i < 4; ++i)
#pragma unroll
      for (int j = 0; j < 2; ++j)
        acc[i][j] = __builtin_amdgcn_mfma_f32_16x16x32_bf16(aF[i], bF[j], acc[i][j], 0, 0, 0);
    __syncthreads();
  }
#pragma unroll
  for (int i = 0; i < 4; ++i)
#pragma unroll
    for (int j = 0; j < 2; ++j)
#pragma unroll
      for (int r = 0; r < 4; ++r) {
        int eg = ebase + wr * 64 + i * 16 + (l >> 4) * 4 + r;
        int tg = tokbase + wc * 32 + j * 16 + (l & 15);
        outT[(size_t)eg * NTOK + tg] = (bf16)(acc[i][j][r] + bv[eg]);
      }
}

__device__ void projB_body(int bidx, const float* __restrict__ head,
                           const int* __restrict__ hidx,
                           const float* __restrict__ Wp,
                           const float* __restrict__ bv,
                           bf16* __restrict__ selO, char* lds) {
  char* ldsA = lds;           // [128 tok][32 d], stride 80
  char* ldsB = lds + 10240;   // [64 e][32 d], stride 80
  const int tid = threadIdx.x, l = tid & 63, w = tid >> 6;
  const int tokbase = (bidx >> 3) * 128;
  const int ebase   = (bidx & 7) * 64;
  const int wr = w & 1, wc = w >> 1;
  f32x4 acc[4][2] = {};
  const int arow = tid >> 1, ahalf = tid & 1;
  const int brow = tid >> 2, bgr = tid & 3;
  const int flat = tokbase + arow;
  const int bb = flat >> 11;
  const int hv = hidx[flat];
  const float* aS = head + ((size_t)bb * 2049 + hv) * 1024 + ahalf * 16;
  const float* bS = Wp + (size_t)(ebase + brow) * 1024 + bgr * 8;
  const int lo = (l & 15) * 80 + (l >> 4) * 16;
  for (int kb = 0; kb < 1024; kb += 32) {
    float4 a0 = *(const float4*)(aS + kb);
    float4 a1 = *(const float4*)(aS + kb + 4);
    float4 a2 = *(const float4*)(aS + kb + 8);
    float4 a3 = *(const float4*)(aS + kb + 12);
    float4 b0 = *(const float4*)(bS + kb);
    float4 b1 = *(const float4*)(bS + kb + 4);
    *(bf16x8*)(ldsA + arow * 80 + ahalf * 32)      = cvt8(a0, a1);
    *(bf16x8*)(ldsA + arow * 80 + ahalf * 32 + 16) = cvt8(a2, a3);
    *(bf16x8*)(ldsB + brow * 80 + bgr * 16)        = cvt8(b0, b1);
    __syncthreads();
    bf16x8 aF[4], bF[2];
#pragma unroll
    for (int i = 0; i < 4; ++i) aF[i] = *(bf16x8*)(ldsA + (wr * 64 + i * 16) * 80 + lo);
#pragma unroll
    for (int j = 0; j < 2; ++j) bF[j] = *(bf16x8*)(ldsB + (wc * 32 + j * 16) * 80 + lo);
#pragma unroll
    for (int i = 0; i < 4; ++i)
#pragma unroll
      for (int j = 0; j < 2; ++j)
        acc[i][j] = __builtin_amdgcn_mfma_f32_16x16x32_bf16(aF[i], bF[j], acc[i][j], 0, 0, 0);
    __syncthreads();
  }
#pragma unroll
  for (int i = 0; i < 4; ++i)
#pragma unroll
    for (int j = 0; j < 2; ++j)
#pragma unroll
      for (int r = 0; r < 4; ++r) {
        int tg = tokbase + wr * 64 + i * 16 + (l >> 4) * 4 + r;
        int eg = ebase + wc * 32 + j * 16 + (l & 15);
        selO[(size_t)tg * DLBL + eg] = (bf16)(acc[i][j][r] + bv[eg]);
      }
}

__global__ __launch_bounds__(256) void prep_k(const float* __restrict__ W,
                                              bf16* __restrict__ Wb,
                                              const float* __restrict__ dep_W,
                                              const float* __restrict__ dep,
                                              const float* __restrict__ dep_b,
                                              bf16* __restrict__ depT,
                                              const float* __restrict__ head,
                                              const int* __restrict__ hidx,
                                              const float* __restrict__ head_W,
                                              const float* __restrict__ head_b,
                                              bf16* __restrict__ selB) {
  __shared__ char lds[15360];
  const int b = blockIdx.x;
  if (b < 256) {
    projA_body(b, dep_W, dep, dep_b, depT, lds);
  } else if (b < 512) {
    projB_body(b - 256, head, hidx, head_W, head_b, selB, lds);
  } else {
    int i = (b - 512) * 256 + threadIdx.x;
    const float4* s = (const float4*)W + (size_t)i * 2;
    float4 a = s[0], c = s[1];
    *(bf16x8*)(Wb + (size_t)i * 8) = cvt8(a, c);
  }
}

// ---------------------------------------------------------------------------
// Kernel 4 v12 == r5 VERBATIM (125.8us, MfmaUtil 38.3, Occ 39, proven):
// 128d x 256tok, 16x16x32, BK=32, 3-buffer 72KB LDS, 2 blocks/CU via
// __launch_bounds__(512,4), ds_read FIRST then STG(t+2) then MFMA, counted
// vmcnt(3), 1 barrier/K-tile, setprio. Shfl-only epilogue, 8 parts slices.
// ---------------------------------------------------------------------------
__global__ __launch_bounds__(512, 4) void biaff_k(const bf16* __restrict__ Wb,
                                                  const bf16* __restrict__ sel,
                                                  const bf16* __restrict__ depT,
                                                  float* __restrict__ parts) {
  __shared__ char lds[73728];          // 3 x (A 8KB + B 16KB)
  const int tid = threadIdx.x, l = tid & 63, w = tid >> 6;

  // bijective XCD-aware decode: combo fast, tok slow (r5-proven)
  const int lin = blockIdx.x;
  const int xcd = lin & 7, idx = lin >> 3;   // idx 0..399
  const int sub = idx % 25;
  const int bx  = idx / 25;                  // tok tile 0..15
  const int combo = xcd * 25 + sub;          // 0..199
  const int n  = combo % 50;
  const int dz = combo / 50;                 // 0..3
  const int tokbase = bx * 256;
  const int dbase   = dz * 128;

  const int wd = w >> 2, wt = w & 3;         // wave tile: 64 d x 64 tok
  f32x4 acc[4][4] = {};

  const int srow = l >> 2;
  const int schunk = ((l & 3) ^ ((l >> 3) & 3)) * 8;
  const bf16* aG = Wb  + ((size_t)(n * DLBL + dbase + w * 16 + srow)) * DLBL + schunk;
  const bf16* bG = sel + ((size_t)(tokbase + w * 32 + srow)) * DLBL + schunk;
  const int aOff = w * 1024;                 // w*16 rows * 64B
  const int bOff = 8192 + w * 2048;          // w*32 rows * 64B

  const int lq = l & 15, lh = l >> 4;
  const int ro = lh ^ ((lq >> 1) & 3);
  const char* rdA = lds + (wd * 64 + lq) * 64 + ro * 16;
  const char* rdB = lds + 8192 + (wt * 64 + lq) * 64 + ro * 16;

#define STG(T) do { \
    const bf16* a_ = aG + (T) * 32; \
    const bf16* b_ = bG + (T) * 32; \
    char* la_ = lds + ((T) % 3) * 24576 + aOff; \
    char* lb_ = lds + ((T) % 3) * 24576 + bOff; \
    gl16(a_, la_); \
    gl16(b_, lb_); \
    gl16(b_ + 16 * DLBL, lb_ + 1024); \
  } while (0)
#define WAITV(N) asm volatile("s_waitcnt vmcnt(" #N ")" ::: "memory")
#define PHASE(T, DOSTG, DOWV3, DOWV0, DOBAR) do { \
    const char* cA = rdA + ((T) % 3) * 24576; \
    const char* cB = rdB + ((T) % 3) * 24576; \
    bf16x8 aF[4], bF[4]; \
    aF[0] = *(const bf16x8*)(cA + 0 * 1024); \
    aF[1] = *(const bf16x8*)(cA + 1 * 1024); \
    aF[2] = *(const bf16x8*)(cA + 2 * 1024); \
    aF[3] = *(const bf16x8*)(cA + 3 * 1024); \
    bF[0] = *(const bf16x8*)(cB + 0 * 1024); \
    bF[1] = *(const bf16x8*)(cB + 1 * 1024); \
    bF[2] = *(const bf16x8*)(cB + 2 * 1024); \
    bF[3] = *(const bf16x8*)(cB + 3 * 1024); \
    if (DOSTG) STG((T) + 2); \
    __builtin_amdgcn_s_setprio(1); \
    _Pragma("unroll") \
    for (int i = 0; i < 4; ++i) \
      _Pragma("unroll") \
      for (int j = 0; j < 4; ++j) \
        acc[i][j] = __builtin_amdgcn_mfma_f32_16x16x32_bf16(aF[i], bF[j], acc[i][j], 0, 0, 0); \
    __builtin_amdgcn_s_setprio(0); \
    if (DOWV3) WAITV(3); \
    if (DOWV0) WAITV(0); \
    if (DOBAR) __builtin_amdgcn_s_barrier(); \
  } while (0)

  // prologue: stage tiles 0,1 (6 loads/wave); certify tile 0 (drain to 3)
  STG(0); STG(1);
  WAITV(3);
  __builtin_amdgcn_s_barrier();

  PHASE(0, 1, 1, 0, 1);  PHASE(1, 1, 1, 0, 1);  PHASE(2, 1, 1, 0, 1);
  PHASE(3, 1, 1, 0, 1);  PHASE(4, 1, 1, 0, 1);  PHASE(5, 1, 1, 0, 1);
  PHASE(6, 1, 1, 0, 1);  PHASE(7, 1, 1, 0, 1);  PHASE(8, 1, 1, 0, 1);
  PHASE(9, 1, 1, 0, 1);  PHASE(10, 1, 1, 0, 1); PHASE(11, 1, 1, 0, 1);
  PHASE(12, 1, 1, 0, 1); PHASE(13, 1, 1, 0, 1);
  PHASE(14, 0, 0, 1, 1);                      // no stage; certify tile 15
  PHASE(15, 0, 0, 0, 0);                      // final tile, no sync needed

#undef PHASE
#undef WAITV
#undef STG

  // ---- epilogue: H[d,t] * depT[d,t], reduce over the wave's 64 d ----
  float p[4] = {0.f, 0.f, 0.f, 0.f};
#pragma unroll
  for (int j = 0; j < 4; ++j) {
    const int tg = tokbase + wt * 64 + j * 16 + lq;
#pragma unroll
    for (int i = 0; i < 4; ++i)
#pragma unroll
      for (int r = 0; r < 4; ++r) {
        int dg = dbase + wd * 64 + i * 16 + lh * 4 + r;
        p[j] += acc[i][j][r] * (float)depT[(size_t)dg * NTOK + tg];
      }
  }
#pragma unroll
  for (int j = 0; j < 4; ++j) {
    p[j] += __shfl_xor(p[j], 16);
    p[j] += __shfl_xor(p[j], 32);
  }
  if (l < 16) {
#pragma unroll
    for (int j = 0; j < 4; ++j) {
      int tg = tokbase + wt * 64 + j * 16 + l;
      parts[(size_t)(dz * 2 + wd) * 204800 + (size_t)tg * NLAB + n] = p[j];
    }
  }
}

// ---------------------------------------------------------------------------
// Kernel 5: sum the 8 d-partials + bias -> logits [4096][50] f32
// ---------------------------------------------------------------------------
__global__ __launch_bounds__(256) void fin_k(const float* __restrict__ parts,
                                             const float* __restrict__ bias,
                                             float* __restrict__ out) {
  int i = blockIdx.x * 256 + threadIdx.x;
  float v = 0.f;
#pragma unroll
  for (int q = 0; q < 8; ++q) v += parts[(size_t)q * 204800 + i];
  out[i] = v + bias[i % NLAB];
}

// ---------------------------------------------------------------------------
extern "C" void kernel_launch(void* const* d_in, const int* in_sizes, int n_in,
                              void* d_out, int out_size, void* d_ws, size_t ws_size,
                              hipStream_t stream) {
  const float* dep    = (const float*)d_in[0];
  const float* head   = (const float*)d_in[1];
  const int*   hidx   = (const int*)d_in[2];
  const float* dep_W  = (const float*)d_in[4];
  const float* dep_b  = (const float*)d_in[5];
  const float* head_W = (const float*)d_in[6];
  const float* head_b = (const float*)d_in[7];
  const float* W      = (const float*)d_in[8];
  const float* bias   = (const float*)d_in[9];
  float* out = (float*)d_out;

  char* ws = (char*)d_ws;
  bf16*  Wb    = (bf16*)(ws);
  bf16*  depT  = (bf16*)(ws + 26214400);
  bf16*  selB  = (bf16*)(ws + 30408704);
  float* parts = (float*)(ws + 34603008);   // 8 * 204800 f32
  if (ws_size < (size_t)41156608) return;

  hipLaunchKernelGGL(prep_k, dim3(6912), dim3(256), 0, stream,
                     W, Wb, dep_W, dep, dep_b, depT, head, hidx, head_W, head_b, selB);
  hipLaunchKernelGGL(biaff_k, dim3(3200), dim3(512), 0, stream,
                     Wb, selB, depT, parts);
  hipLaunchKernelGGL(fin_k, dim3(800), dim3(256), 0, stream, parts, bias, out);
}